// Round 17
// baseline (4080.613 us; speedup 1.0000x reference)
//
#include <hip/hip_runtime.h>
#include <hip/hip_bf16.h>

#define Bsz 2
#define Tsz 1024
#define Vsz 50257
#define Csz 768
#define Lsz 12
#define Hsz 12
#define Msz 2048  // B*T
#define VPAD 50304  // Vsz rounded up to 128

typedef __attribute__((ext_vector_type(8))) short short8;
typedef __attribute__((ext_vector_type(4))) float f32x4;

__device__ __forceinline__ ushort f2bf(float f) {
  union { float f; unsigned u; } v; v.f = f;
  return (ushort)((v.u + 0x7FFFu + ((v.u >> 16) & 1u)) >> 16);
}

__device__ __forceinline__ void load_lds16(const void* g, void* l) {
  __builtin_amdgcn_global_load_lds(
      (const __attribute__((address_space(1))) unsigned int*)g,
      (__attribute__((address_space(3))) unsigned int*)l, 16, 0, 0);
}

// ---------------- embedding + row stats (sum, sumsq) ----------------
__global__ void k_embed(const int* __restrict__ idx, const float* __restrict__ wte,
                        const float* __restrict__ wpe, float* __restrict__ x,
                        float* __restrict__ st0) {
  int m = blockIdx.x;
  int t = m & (Tsz - 1);
  const float* src = wte + (size_t)idx[m] * Csz;
  const float* pe  = wpe + (size_t)t * Csz;
  float* dst = x + (size_t)m * Csz;
  int tid = threadIdx.x;
  float v0 = src[tid] + pe[tid];
  float v1 = src[tid + 256] + pe[tid + 256];
  float v2 = src[tid + 512] + pe[tid + 512];
  dst[tid] = v0; dst[tid + 256] = v1; dst[tid + 512] = v2;
  float s = v0 + v1 + v2, q = v0 * v0 + v1 * v1 + v2 * v2;
  for (int o = 32; o; o >>= 1) {
    s += __shfl_down(s, o, 64);
    q += __shfl_down(q, o, 64);
  }
  __shared__ float red[8];
  int wid = tid >> 6, lane = tid & 63;
  if (!lane) { red[wid] = s; red[4 + wid] = q; }
  __syncthreads();
  if (!tid) {
    st0[m * 2]     = red[0] + red[1] + red[2] + red[3];
    st0[m * 2 + 1] = red[4] + red[5] + red[6] + red[7];
  }
}

// ---------------- batched weight prep: transpose f32 [R][Cn] -> bf16 [Cn][R] ----------------
__global__ void k_prep(const float* __restrict__ aw, const float* __restrict__ pw,
                       const float* __restrict__ fw, const float* __restrict__ f2w,
                       ushort* __restrict__ wT, int l0, size_t lstride) {
  int t = blockIdx.x;
  int ly = l0 + blockIdx.y;
  const float* src; int R, Cn; size_t doff;
  if (t < 1728)      { src = aw  + (size_t)ly * Csz * 3 * Csz; R = Csz;     Cn = 3 * Csz; doff = 0; }
  else if (t < 2304) { t -= 1728; src = pw  + (size_t)ly * Csz * Csz;     R = Csz;     Cn = Csz;     doff = (size_t)3 * Csz * Csz; }
  else if (t < 4608) { t -= 2304; src = fw  + (size_t)ly * Csz * 4 * Csz; R = Csz;     Cn = 4 * Csz; doff = (size_t)4 * Csz * Csz; }
  else               { t -= 4608; src = f2w + (size_t)ly * 4 * Csz * Csz; R = 4 * Csz; Cn = Csz;     doff = (size_t)8 * Csz * Csz; }
  ushort* dst = wT + (size_t)blockIdx.y * lstride + doff;

  __shared__ float tb[32][33];
  int ncx = Cn / 32;
  int c0 = (t % ncx) * 32, r0 = (t / ncx) * 32;
  int tx = threadIdx.x & 31, ty = threadIdx.x >> 5;  // 32 x 8
#pragma unroll
  for (int k = 0; k < 4; k++)
    tb[ty + 8 * k][tx] = src[(size_t)(r0 + ty + 8 * k) * Cn + c0 + tx];
  __syncthreads();
#pragma unroll
  for (int k = 0; k < 4; k++)
    dst[(size_t)(c0 + ty + 8 * k) * R + r0 + tx] = f2bf(tb[tx][ty + 8 * k]);
}

// ---------------- f32 -> bf16 elementwise with zero-padded tail ----------------
__global__ void k_f32_to_bf16_pad(const float* __restrict__ src, ushort* __restrict__ dst,
                                  int n_src, int n_tot) {
  int stride = gridDim.x * 256 * 4;
  for (int i = (blockIdx.x * 256 + threadIdx.x) * 4; i < n_tot; i += stride) {
    ushort4 o;
    if (i + 3 < n_src) {
      float4 v = *(const float4*)(src + i);
      o.x = f2bf(v.x); o.y = f2bf(v.y); o.z = f2bf(v.z); o.w = f2bf(v.w);
    } else {
      o.x = o.y = o.z = o.w = 0;
    }
    *(ushort4*)(dst + i) = o;
  }
}

// ---------------- templated GEMM ----------------
// out[M][N] = A[M][K]bf16 @ Bt[N][K]bf16.
// OUT=0: f32 +bias +res; 1: bf16 +bias; 2: bf16 gelu(acc+bias);
// OUT=3: bf16 +bias, cols<768 scaled by 0.125*log2e (q pre-scale for exp2-softmax).
// LNA: A-operand = LayerNorm(xln) computed on the fly during staging (reg-load f32 x,
//      apply (v-mean)*rstd*lnw+lnb from stin row stats {sum,sumsq}, pack bf16,
//      ds_write_b128 to the swizzled slot). Requires BK=64, K=768 row stride.
// STATS: OUT=0 epilogue also accumulates per-row {sum,sumsq} of the written x into
//      stout via lane-group shfl reduce + atomicAdd (stout zeroed by host memset).
// PIPE=1: double-buffered, STAGE(t+1) before COMPUTE(t). PIPE=0: single-buffer (lm_head).
// T2 swizzle on B staging + all reads. m-fastest mapping; Bt padded to n0+BN rows.
template <int BM, int BN, int FM, int FN, int BK, int OUT, bool SWZ, bool PIPE, int MINW,
          bool LNA, bool STATS>
__global__ __launch_bounds__(256, MINW) void k_gemm(
    const ushort* __restrict__ A, const ushort* __restrict__ Bt,
    const float* __restrict__ bias, const float* res,
    void* __restrict__ outv, int N, int K, int ntm,
    const float* __restrict__ xln, const float* __restrict__ stin,
    const float* __restrict__ lnw, const float* __restrict__ lnb,
    float* __restrict__ stout) {
  constexpr int RPC = (BK == 64) ? 8 : 16;          // rows per 1KB chunk
  constexpr int NCHA = BM / RPC, NCH = (BM + BN) / RPC, CPW = NCH / 4;
  static_assert(NCH % 4 == 0, "chunk count must be divisible by wave count");
  static_assert(!LNA || BK == 64, "LNA path implemented for BK=64 only");
  constexpr int NBUF = PIPE ? 2 : 1;
  __shared__ __align__(16) ushort smem[NBUF * (BM + BN) * BK];

  int bid = blockIdx.x;
  if (SWZ) {
    int nwg = gridDim.x;
    bid = (bid & 7) * (nwg >> 3) + (bid >> 3);
  }
  int by = bid % ntm, bx = bid / ntm;
  int m0 = by * BM, n0 = bx * BN;

  int tid = threadIdx.x;
  int wid = tid >> 6, lane = tid & 63, lg = lane >> 4, lr = lane & 15;
  int wm = (wid >> 1) * (FM * 16), wn = (wid & 1) * (FN * 16);

  const f32x4 FZ = {0.f, 0.f, 0.f, 0.f};
  f32x4 acc[FM][FN];
#pragma unroll
  for (int i = 0; i < FM; i++)
#pragma unroll
    for (int j = 0; j < FN; j++) acc[i][j] = FZ;

  int srow, scol;
  if (BK == 64) { srow = lane >> 3; scol = ((lane & 7) ^ (srow & 7)) * 8; }
  else          { srow = lane >> 2; scol = ((lane & 3) ^ ((lane >> 3) & 3)) * 8; }

  const ushort* p[CPW];
  int ldso[CPW];
#pragma unroll
  for (int i = 0; i < CPW; i++) {
    int c = wid * CPW + i;
    ldso[i] = c * 512;
    if (c < NCHA) {
      if (!LNA) p[i] = A + (size_t)(m0 + c * RPC + srow) * K + scol;
      else      p[i] = nullptr;
    } else {
      p[i] = Bt + (size_t)(n0 + (c - NCHA) * RPC + srow) * K + scol;
    }
  }

  auto STAGE = [&](int buf, int k0) {
    ushort* Sb = smem + buf * (BM + BN) * BK;
#pragma unroll
    for (int i = 0; i < CPW; i++) {
      int c = wid * CPW + i;
      if (LNA && c < NCHA) {
        int r = lane >> 3, ls = lane & 7;
        int grow = m0 + c * 8 + r;
        float sm = stin[grow * 2], s2 = stin[grow * 2 + 1];
        float mean = sm * (1.f / Csz);
        float rstd = rsqrtf(s2 * (1.f / Csz) - mean * mean + 1e-5f);
        const float* xp = xln + (size_t)grow * Csz + k0 + ls * 8;
        float4 x0 = *(const float4*)xp, x1 = *(const float4*)(xp + 4);
        const float* wp = lnw + k0 + ls * 8;
        const float* bp = lnb + k0 + ls * 8;
        float4 w0 = *(const float4*)wp, w1 = *(const float4*)(wp + 4);
        float4 b0 = *(const float4*)bp, b1 = *(const float4*)(bp + 4);
        short8 pk;
        pk[0] = (short)f2bf((x0.x - mean) * rstd * w0.x + b0.x);
        pk[1] = (short)f2bf((x0.y - mean) * rstd * w0.y + b0.y);
        pk[2] = (short)f2bf((x0.z - mean) * rstd * w0.z + b0.z);
        pk[3] = (short)f2bf((x0.w - mean) * rstd * w0.w + b0.w);
        pk[4] = (short)f2bf((x1.x - mean) * rstd * w1.x + b1.x);
        pk[5] = (short)f2bf((x1.y - mean) * rstd * w1.y + b1.y);
        pk[6] = (short)f2bf((x1.z - mean) * rstd * w1.z + b1.z);
        pk[7] = (short)f2bf((x1.w - mean) * rstd * w1.w + b1.w);
        *(short8*)&Sb[(c * 8 + r) * BK + ((ls ^ r) & 7) * 8] = pk;
      } else {
        load_lds16(p[i], Sb + ldso[i]);
        p[i] += BK;
      }
    }
  };
  auto COMPUTE = [&](int buf) {
    const ushort* Sb = smem + buf * (BM + BN) * BK;
#pragma unroll
    for (int kk = 0; kk < BK / 32; kk++) {
      int cofs;
      if (BK == 64) cofs = (kk * 32 + lg * 8) ^ ((lr & 7) << 3);
      else          cofs = (lg * 8) ^ (((lr >> 1) & 3) << 3);
      short8 a[FM], b[FN];
#pragma unroll
      for (int f = 0; f < FM; f++)
        a[f] = *(const short8*)&Sb[(wm + f * 16 + lr) * BK + cofs];
#pragma unroll
      for (int f = 0; f < FN; f++)
        b[f] = *(const short8*)&Sb[(BM + wn + f * 16 + lr) * BK + cofs];
#pragma unroll
      for (int fi = 0; fi < FM; fi++)
#pragma unroll
        for (int fj = 0; fj < FN; fj++)
          acc[fi][fj] = __builtin_amdgcn_mfma_f32_16x16x32_bf16(a[fi], b[fj], acc[fi][fj], 0, 0, 0);
    }
  };

  int NT = K / BK;
  if (PIPE) {
    int kn = BK;
    STAGE(0, 0);
    __syncthreads();
    for (int t = 0;;) {
      if (t + 1 < NT) { STAGE(1, kn); kn += BK; }
      COMPUTE(0);
      if (++t == NT) break;
      __syncthreads();  // drains STAGE(1); buf0 free
      if (t + 1 < NT) { STAGE(0, kn); kn += BK; }
      COMPUTE(1);
      if (++t == NT) break;
      __syncthreads();  // drains STAGE(0); buf1 free
    }
  } else {
    for (int t = 0; t < NT; t++) {
      STAGE(0, t * BK);
      __syncthreads();
      COMPUTE(0);
      __syncthreads();
    }
  }

  float ps[FM][4], pq[FM][4];
  if (STATS) {
#pragma unroll
    for (int fi = 0; fi < FM; fi++)
#pragma unroll
      for (int i = 0; i < 4; i++) { ps[fi][i] = 0.f; pq[fi][i] = 0.f; }
  }

#pragma unroll
  for (int fi = 0; fi < FM; fi++)
#pragma unroll
    for (int fj = 0; fj < FN; fj++) {
      int gn = n0 + wn + fj * 16 + lr;
      if (gn < N) {
        float bv = bias ? bias[gn] : 0.f;
#pragma unroll
        for (int i = 0; i < 4; i++) {
          int gm = m0 + wm + fi * 16 + 4 * lg + i;
          size_t o = (size_t)gm * N + gn;
          float v = acc[fi][fj][i] + bv;
          if (OUT == 0) {
            if (res) v += res[o];
            if (STATS) { ps[fi][i] += v; pq[fi][i] += v * v; }
            ((float*)outv)[o] = v;
          } else if (OUT == 1) {
            ((ushort*)outv)[o] = f2bf(v);
          } else if (OUT == 3) {
            if (gn < Csz) v *= 0.18033688f;  // 0.125 * log2(e): exp2-softmax pre-scale
            ((ushort*)outv)[o] = f2bf(v);
          } else {
            float u = 0.7978845608f * (v + 0.044715f * v * v * v);
            float t2 = __expf(2.f * u);
            float th = 1.f - 2.f / (t2 + 1.f);
            ((ushort*)outv)[o] = f2bf(0.5f * v * (1.f + th));
          }
        }
      }
    }

  if (STATS) {
    // per-row partial {sum, sumsq} over this block's BN columns -> atomicAdd
#pragma unroll
    for (int fi = 0; fi < FM; fi++)
#pragma unroll
      for (int i = 0; i < 4; i++) {
        float a = ps[fi][i], b2 = pq[fi][i];
#pragma unroll
        for (int o = 1; o < 16; o <<= 1) {
          a  += __shfl_xor(a, o, 16);
          b2 += __shfl_xor(b2, o, 16);
        }
        if (lr == 0) {
          int gm = m0 + wm + fi * 16 + 4 * lg + i;
          atomicAdd(stout + gm * 2, a);
          atomicAdd(stout + gm * 2 + 1, b2);
        }
      }
  }
}

// ---------------- flash attention (causal), qkv bf16 -> y bf16 ----------------
// 1-D grid B*H*16 with bijective XCD chunk swizzle; longest-first q0; KVBLK=128.
// Fixed-max exp2 softmax (Q pre-scaled by 0.125*log2e in qkv epilogue).
__global__ __launch_bounds__(256) void k_attn(const ushort* __restrict__ qkv,
                                              ushort* __restrict__ ybf) {
  __shared__ __align__(16) ushort Ks[128 * 72];
  __shared__ __align__(16) ushort Vs[64 * 136];
  __shared__ __align__(16) ushort Ps[4 * 16 * 136];
  int bid = blockIdx.x;
  bid = (bid & 7) * ((Bsz * Hsz * 16) >> 3) + (bid >> 3);
  int bh = bid >> 4;
  int q0 = (15 - (bid & 15)) * 64;
  int b = bh / Hsz, h = bh % Hsz;
  int tid = threadIdx.x, wid = tid >> 6, lane = tid & 63, lg = lane >> 4, lr = lane & 15;
  const ushort* base = qkv + (size_t)b * Tsz * 2304;

  int qt = q0 + wid * 16 + lr;
  const ushort* qp = base + (size_t)qt * 2304 + h * 64;
  short8 aq0 = *(const short8*)(qp + lg * 8);
  short8 aq1 = *(const short8*)(qp + 32 + lg * 8);

  int srow = tid >> 3, soff = (tid & 7) * 8;
  const ushort* kp0 = base + (size_t)srow * 2304 + 768 + h * 64 + soff;
  const ushort* vp0 = kp0 + 768;
  short8 kreg[4], vreg[4];
  auto LOADKV = [&](int k0) {
#pragma unroll
    for (int r = 0; r < 4; r++) {
      kreg[r] = *(const short8*)(kp0 + (size_t)(k0 + r * 32) * 2304);
      vreg[r] = *(const short8*)(vp0 + (size_t)(k0 + r * 32) * 2304);
    }
  };
  auto WRITEKV = [&]() {
#pragma unroll
    for (int r = 0; r < 4; r++) {
      int row = srow + r * 32;
      *(short8*)&Ks[row * 72 + soff] = kreg[r];
#pragma unroll
      for (int j = 0; j < 8; j++) Vs[(soff + j) * 136 + row] = (ushort)vreg[r][j];
    }
  };

  const f32x4 FZ = {0.f, 0.f, 0.f, 0.f};
  f32x4 of[4];
  of[0] = FZ; of[1] = FZ; of[2] = FZ; of[3] = FZ;
  float lrow[4] = {0.f, 0.f, 0.f, 0.f};

  int nkt = (q0 >> 7) + 1;
  LOADKV(0);
  for (int kt = 0; kt < nkt; kt++) {
    int k0 = kt * 128;
    WRITEKV();
    __syncthreads();
    if (kt + 1 < nkt) LOADKV(k0 + 128);

    f32x4 sf[8];
#pragma unroll
    for (int nf = 0; nf < 8; nf++) {
      sf[nf] = FZ;
      short8 b0 = *(const short8*)&Ks[(nf * 16 + lr) * 72 + lg * 8];
      short8 b1 = *(const short8*)&Ks[(nf * 16 + lr) * 72 + 32 + lg * 8];
      sf[nf] = __builtin_amdgcn_mfma_f32_16x16x32_bf16(aq0, b0, sf[nf], 0, 0, 0);
      sf[nf] = __builtin_amdgcn_mfma_f32_16x16x32_bf16(aq1, b1, sf[nf], 0, 0, 0);
    }

    bool last = (kt == nkt - 1);
#pragma unroll
    for (int i = 0; i < 4; i++) {
      int qr = q0 + wid * 16 + 4 * lg + i;
      float rs = 0.f;
#pragma unroll
      for (int nf = 0; nf < 8; nf++) {
        float s = sf[nf][i];
        if (last && k0 + nf * 16 + lr > qr) s = -INFINITY;
        float pv = exp2f(s);
        rs += pv;
        Ps[(wid * 16 + 4 * lg + i) * 136 + nf * 16 + lr] = f2bf(pv);
      }
#pragma unroll
      for (int o = 1; o < 16; o <<= 1) rs += __shfl_xor(rs, o, 16);
      lrow[i] += rs;
    }

    short8 ap[4];
#pragma unroll
    for (int c = 0; c < 4; c++)
      ap[c] = *(const short8*)&Ps[(wid * 16 + lr) * 136 + c * 32 + lg * 8];
#pragma unroll
    for (int df = 0; df < 4; df++) {
#pragma unroll
      for (int c = 0; c < 4; c++) {
        short8 bv = *(const short8*)&Vs[(df * 16 + lr) * 136 + c * 32 + lg * 8];
        of[df] = __builtin_amdgcn_mfma_f32_16x16x32_bf16(ap[c], bv, of[df], 0, 0, 0);
      }
    }
    __syncthreads();
  }

  ushort* yp = ybf + (size_t)b * Tsz * Csz;
#pragma unroll
  for (int df = 0; df < 4; df++)
#pragma unroll
    for (int i = 0; i < 4; i++) {
      int qr = q0 + wid * 16 + 4 * lg + i;
      float v = of[df][i] / lrow[i];
      yp[(size_t)qr * Csz + h * 64 + df * 16 + lr] = f2bf(v);
    }
}

// ---------------- host ----------------
extern "C" void kernel_launch(void* const* d_in, const int* in_sizes, int n_in,
                              void* d_out, int out_size, void* d_ws, size_t ws_size,
                              hipStream_t stream) {
  (void)in_sizes; (void)n_in; (void)out_size;
  const int* idx      = (const int*)d_in[0];
  const float* wte    = (const float*)d_in[1];
  const float* wpe    = (const float*)d_in[2];
  const float* ln1_w  = (const float*)d_in[3];
  const float* ln1_b  = (const float*)d_in[4];
  const float* attn_w = (const float*)d_in[5];
  const float* attn_b = (const float*)d_in[6];
  const float* proj_w = (const float*)d_in[7];
  const float* proj_b = (const float*)d_in[8];
  const float* ln2_w  = (const float*)d_in[9];
  const float* ln2_b  = (const float*)d_in[10];
  const float* fc_w   = (const float*)d_in[11];
  const float* fc_b   = (const float*)d_in[12];
  const float* fc2_w  = (const float*)d_in[13];
  const float* fc2_b  = (const float*)d_in[14];
  const float* lnf_w  = (const float*)d_in[15];
  const float* lnf_b  = (const float*)d_in[16];
  const float* lm_w   = (const float*)d_in[17];
  float* out = (float*)d_out;

  char* ws = (char*)d_ws;
  float*  x     = (float*)(ws + 0);            // 6291456
  ushort* qkvbf = (ushort*)(ws + 6291456);     // 9437184
  ushort* abuf  = (ushort*)(ws + 15728640);    // 3145728 (attn y)
  ushort* hbuf  = (ushort*)(ws + 18874368);    // 12582912
  float*  stats = (float*)(ws + 31457280);     // 25 slots * 2048*2 f32 = 409600
  ushort* lmw   = (ushort*)(ws + 31866880);    // 77266944
  ushort* wT    = (ushort*)(ws + 109133824);   // 12*C*C*2 per layer
  const size_t LSTRIDE = (size_t)12 * Csz * Csz;
  const size_t NEED_FULL = 109133824ull + LSTRIDE * 2 * Lsz;  // ~279.0 MB
  bool full = ws_size >= NEED_FULL;
  const int STSL = 2048 * 2;  // floats per stats slot

  hipMemsetAsync(stats, 0, 25 * STSL * 4, stream);
  k_embed<<<Msz, 256, 0, stream>>>(idx, wte, wpe, x, stats);  // slot 0
  k_f32_to_bf16_pad<<<4096, 256, 0, stream>>>(lm_w, lmw, Vsz * Csz, VPAD * Csz);
  if (full)
    k_prep<<<dim3(6912, Lsz), 256, 0, stream>>>(attn_w, proj_w, fc_w, fc2_w, wT, 0, LSTRIDE);

  for (int l = 0; l < Lsz; l++) {
    ushort* wTl = wT + (full ? (size_t)l * LSTRIDE : 0);
    if (!full)
      k_prep<<<dim3(6912, 1), 256, 0, stream>>>(attn_w, proj_w, fc_w, fc2_w, wTl, l, 0);
    const ushort* qkvW = wTl;
    const ushort* projW = wTl + (size_t)3 * Csz * Csz;
    const ushort* fcW   = wTl + (size_t)4 * Csz * Csz;
    const ushort* fc2W  = wTl + (size_t)8 * Csz * Csz;

    // qkv: LN1 fused into A-staging (stats slot 2l), q pre-scaled (OUT=3)
    k_gemm<128, 96, 4, 3, 64, 3, false, true, 1, true, false>
        <<<(Msz / 128) * (3 * Csz / 96), 256, 0, stream>>>(
        nullptr, qkvW, attn_b + (size_t)l * 3 * Csz, nullptr, qkvbf, 3 * Csz, Csz, Msz / 128,
        x, stats + (size_t)(2 * l) * STSL, ln1_w + l * Csz, ln1_b + l * Csz, nullptr);
    k_attn<<<Bsz * Hsz * 16, 256, 0, stream>>>(qkvbf, abuf);
    // proj: writes x (+res) and stats slot 2l+1
    k_gemm<64, 96, 2, 3, 64, 0, false, true, 1, false, true>
        <<<(Msz / 64) * (Csz / 96), 256, 0, stream>>>(
        abuf, projW, proj_b + (size_t)l * Csz, x, x, Csz, Csz, Msz / 64,
        nullptr, nullptr, nullptr, nullptr, stats + (size_t)(2 * l + 1) * STSL);
    // fc: LN2 fused into A-staging (stats slot 2l+1), gelu epilogue
    k_gemm<128, 128, 4, 4, 64, 2, false, true, 1, true, false>
        <<<(Msz / 128) * (4 * Csz / 128), 256, 0, stream>>>(
        nullptr, fcW, fc_b + (size_t)l * 4 * Csz, nullptr, hbuf, 4 * Csz, Csz, Msz / 128,
        x, stats + (size_t)(2 * l + 1) * STSL, ln2_w + l * Csz, ln2_b + l * Csz, nullptr);
    // fc2: writes x (+res) and stats slot 2l+2
    k_gemm<64, 96, 2, 3, 64, 0, false, true, 1, false, true>
        <<<(Msz / 64) * (Csz / 96), 256, 0, stream>>>(
        hbuf, fc2W, fc2_b + (size_t)l * Csz, x, x, Csz, 4 * Csz, Msz / 64,
        nullptr, nullptr, nullptr, nullptr, stats + (size_t)(2 * l + 2) * STSL);
  }

  // lm_head: LNF fused into A-staging (stats slot 24); R6-proven single-buffer BK=64 config
  int ntm = Msz / 64;
  k_gemm<64, 128, 2, 4, 64, 0, true, false, 1, true, false>
      <<<ntm * (VPAD / 128), 256, 0, stream>>>(
      nullptr, lmw, nullptr, nullptr, out, Vsz, Csz, ntm,
      x, stats + (size_t)24 * STSL, lnf_w, lnf_b, nullptr);
}

// Round 18
// 2308.447 us; speedup vs baseline: 1.7677x; 1.7677x over previous
//
#include <hip/hip_runtime.h>
#include <hip/hip_bf16.h>

#define Bsz 2
#define Tsz 1024
#define Vsz 50257
#define Csz 768
#define Lsz 12
#define Hsz 12
#define Msz 2048  // B*T
#define VPAD 50304  // Vsz rounded up to 128

typedef __attribute__((ext_vector_type(8))) short short8;
typedef __attribute__((ext_vector_type(4))) float f32x4;

__device__ __forceinline__ ushort f2bf(float f) {
  union { float f; unsigned u; } v; v.f = f;
  return (ushort)((v.u + 0x7FFFu + ((v.u >> 16) & 1u)) >> 16);
}

__device__ __forceinline__ void load_lds16(const void* g, void* l) {
  __builtin_amdgcn_global_load_lds(
      (const __attribute__((address_space(1))) unsigned int*)g,
      (__attribute__((address_space(3))) unsigned int*)l, 16, 0, 0);
}

// ---------------- embedding ----------------
__global__ void k_embed(const int* __restrict__ idx, const float* __restrict__ wte,
                        const float* __restrict__ wpe, float* __restrict__ x) {
  int m = blockIdx.x;
  int t = m & (Tsz - 1);
  const float* src = wte + (size_t)idx[m] * Csz;
  const float* pe  = wpe + (size_t)t * Csz;
  float* dst = x + (size_t)m * Csz;
  for (int c = threadIdx.x; c < Csz; c += 256)
    dst[c] = src[c] + pe[c];
}

// ---------------- layernorm (f32 in -> bf16 out), 4 rows/block, wave-level ----------------
__global__ void k_ln(const float* __restrict__ x, const float* __restrict__ w,
                     const float* __restrict__ b, ushort* __restrict__ out) {
  int r = blockIdx.x * 4 + (threadIdx.x >> 6);
  int lane = threadIdx.x & 63;
  const float* row = x + (size_t)r * Csz;
  float v[12];
  float s = 0.f, q = 0.f;
#pragma unroll
  for (int j = 0; j < 12; j++) {
    v[j] = row[lane + j * 64];
    s += v[j];
    q += v[j] * v[j];
  }
#pragma unroll
  for (int o = 1; o < 64; o <<= 1) {
    s += __shfl_xor(s, o, 64);
    q += __shfl_xor(q, o, 64);
  }
  float mean = s * (1.0f / Csz);
  float rstd = rsqrtf(q * (1.0f / Csz) - mean * mean + 1e-5f);
  ushort* o = out + (size_t)r * Csz;
#pragma unroll
  for (int j = 0; j < 12; j++) {
    int c = lane + j * 64;
    o[c] = f2bf((v[j] - mean) * rstd * w[c] + b[c]);
  }
}

// ---------------- batched weight prep: transpose f32 [R][Cn] -> bf16 [Cn][R] ----------------
__global__ void k_prep(const float* __restrict__ aw, const float* __restrict__ pw,
                       const float* __restrict__ fw, const float* __restrict__ f2w,
                       ushort* __restrict__ wT, int l0, size_t lstride) {
  int t = blockIdx.x;
  int ly = l0 + blockIdx.y;
  const float* src; int R, Cn; size_t doff;
  if (t < 1728)      { src = aw  + (size_t)ly * Csz * 3 * Csz; R = Csz;     Cn = 3 * Csz; doff = 0; }
  else if (t < 2304) { t -= 1728; src = pw  + (size_t)ly * Csz * Csz;     R = Csz;     Cn = Csz;     doff = (size_t)3 * Csz * Csz; }
  else if (t < 4608) { t -= 2304; src = fw  + (size_t)ly * Csz * 4 * Csz; R = Csz;     Cn = 4 * Csz; doff = (size_t)4 * Csz * Csz; }
  else               { t -= 4608; src = f2w + (size_t)ly * 4 * Csz * Csz; R = 4 * Csz; Cn = Csz;     doff = (size_t)8 * Csz * Csz; }
  ushort* dst = wT + (size_t)blockIdx.y * lstride + doff;

  __shared__ float tb[32][33];
  int ncx = Cn / 32;
  int c0 = (t % ncx) * 32, r0 = (t / ncx) * 32;
  int tx = threadIdx.x & 31, ty = threadIdx.x >> 5;  // 32 x 8
#pragma unroll
  for (int k = 0; k < 4; k++)
    tb[ty + 8 * k][tx] = src[(size_t)(r0 + ty + 8 * k) * Cn + c0 + tx];
  __syncthreads();
#pragma unroll
  for (int k = 0; k < 4; k++)
    dst[(size_t)(c0 + ty + 8 * k) * R + r0 + tx] = f2bf(tb[tx][ty + 8 * k]);
}

// ---------------- f32 -> bf16 elementwise with zero-padded tail ----------------
__global__ void k_f32_to_bf16_pad(const float* __restrict__ src, ushort* __restrict__ dst,
                                  int n_src, int n_tot) {
  int stride = gridDim.x * 256 * 4;
  for (int i = (blockIdx.x * 256 + threadIdx.x) * 4; i < n_tot; i += stride) {
    ushort4 o;
    if (i + 3 < n_src) {
      float4 v = *(const float4*)(src + i);
      o.x = f2bf(v.x); o.y = f2bf(v.y); o.z = f2bf(v.z); o.w = f2bf(v.w);
    } else {
      o.x = o.y = o.z = o.w = 0;
    }
    *(ushort4*)(dst + i) = o;
  }
}

// ---------------- templated GEMM ----------------
// out[M][N] = A[M][K]bf16 @ Bt[N][K]bf16.
// OUT=0: f32 +bias +res; 1: bf16 +bias; 2: bf16 gelu(acc+bias);
// OUT=3: bf16 +bias, cols<768 scaled by 0.125*log2e (q pre-scale for exp2-softmax).
// outv must NOT alias A. 4 waves 2x2; wave tile (FM*16)x(FN*16).
// T2 swizzle on staging+reads. Loop modes:
//   PIPE=1: double-buffered, STAGE(t+1) before COMPUTE(t), K/BK even. BK=64 for compute
//           GEMMs (fewer, fatter phases — BK=32 regressed ~110us in R14, m233 lesson).
//   PIPE=0: single-buffer 2-barrier loop, minimal LDS/VGPR (BW-bound lm_head: best at ~43-64% occ, R6).
// NOTE (R17 lesson): do NOT fuse LN into A-staging — LN would be recomputed per n-tile
// (x re-read f32 per tile; lm_head 316->647us). Materialize LN once via k_ln.
// MINW = __launch_bounds__ min-waves-per-EU.
// BK=32 requires (BM+BN)%64==0; BK=64 requires (BM+BN)%32==0 (chunk map).
// EPI=1 (FN=4, bias/res null): FM-pass LDS-transpose epilogue -> f32x4 row stores.
template <int BM, int BN, int FM, int FN, int BK, int OUT, bool SWZ, int EPI, bool PIPE, int MINW>
__global__ __launch_bounds__(256, MINW) void k_gemm(
    const ushort* __restrict__ A, const ushort* __restrict__ Bt,
    const float* __restrict__ bias, const float* res,
    void* __restrict__ outv, int N, int K, int ntm) {
  constexpr int RPC = (BK == 64) ? 8 : 16;          // rows per 1KB chunk
  constexpr int NCHA = BM / RPC, NCH = (BM + BN) / RPC, CPW = NCH / 4;
  static_assert(NCH % 4 == 0, "chunk count must be divisible by wave count");
  constexpr int NBUF = PIPE ? 2 : 1;
  constexpr int STB = NBUF * (BM + BN) * BK * 2;    // staging bytes
  constexpr int EPB = EPI ? (4 * 16 * 68 * 4) : 0;  // epilogue bytes (per wave 16x68 f32)
  constexpr int SMB = STB > EPB ? STB : EPB;
  __shared__ __align__(16) char smem[SMB];

  int bid = blockIdx.x;
  if (SWZ) {
    int nwg = gridDim.x;
    bid = (bid & 7) * (nwg >> 3) + (bid >> 3);
  }
  int by = bid % ntm, bx = bid / ntm;
  int m0 = by * BM, n0 = bx * BN;

  int tid = threadIdx.x;
  int wid = tid >> 6, lane = tid & 63, lg = lane >> 4, lr = lane & 15;
  int wm = (wid >> 1) * (FM * 16), wn = (wid & 1) * (FN * 16);

  const f32x4 FZ = {0.f, 0.f, 0.f, 0.f};
  f32x4 acc[FM][FN];
#pragma unroll
  for (int i = 0; i < FM; i++)
#pragma unroll
    for (int j = 0; j < FN; j++) acc[i][j] = FZ;

  int srow, scol;
  if (BK == 64) { srow = lane >> 3; scol = ((lane & 7) ^ (srow & 7)) * 8; }
  else          { srow = lane >> 2; scol = ((lane & 3) ^ ((lane >> 3) & 3)) * 8; }

  const ushort* p[CPW];
  int ldso[CPW];
#pragma unroll
  for (int i = 0; i < CPW; i++) {
    int c = wid * CPW + i;
    ldso[i] = c * 512;
    if (c < NCHA) p[i] = A + (size_t)(m0 + c * RPC + srow) * K + scol;
    else          p[i] = Bt + (size_t)(n0 + (c - NCHA) * RPC + srow) * K + scol;
  }

  auto STAGE = [&](int buf) {
    ushort* Sb = (ushort*)smem + buf * (BM + BN) * BK;
#pragma unroll
    for (int i = 0; i < CPW; i++) {
      load_lds16(p[i], Sb + ldso[i]);
      p[i] += BK;
    }
  };
  auto COMPUTE = [&](int buf) {
    const ushort* Sb = (const ushort*)smem + buf * (BM + BN) * BK;
#pragma unroll
    for (int kk = 0; kk < BK / 32; kk++) {
      int cofs;
      if (BK == 64) cofs = (kk * 32 + lg * 8) ^ ((lr & 7) << 3);
      else          cofs = (lg * 8) ^ (((lr >> 1) & 3) << 3);
      short8 a[FM], b[FN];
#pragma unroll
      for (int f = 0; f < FM; f++)
        a[f] = *(const short8*)&Sb[(wm + f * 16 + lr) * BK + cofs];
#pragma unroll
      for (int f = 0; f < FN; f++)
        b[f] = *(const short8*)&Sb[(BM + wn + f * 16 + lr) * BK + cofs];
#pragma unroll
      for (int fi = 0; fi < FM; fi++)
#pragma unroll
        for (int fj = 0; fj < FN; fj++)
          acc[fi][fj] = __builtin_amdgcn_mfma_f32_16x16x32_bf16(a[fi], b[fj], acc[fi][fj], 0, 0, 0);
    }
  };

  if (PIPE) {
    int NT = K / BK;  // even by contract
    STAGE(0);
    __syncthreads();
    for (int t = 0;;) {
      if (t + 1 < NT) STAGE(1);
      COMPUTE(0);
      if (++t == NT) break;
      __syncthreads();  // drains STAGE(1); buf0 free
      if (t + 1 < NT) STAGE(0);
      COMPUTE(1);
      if (++t == NT) break;
      __syncthreads();  // drains STAGE(0); buf1 free
    }
  } else {
    int NT = K / BK;
    for (int t = 0; t < NT; t++) {
      STAGE(0);
      __syncthreads();  // vmcnt drained by compiler before barrier
      COMPUTE(0);
      __syncthreads();
    }
  }

  if constexpr (EPI) {
    // FM-pass LDS-transpose epilogue (FN=4): per pass one 16x64 f32 frag-row per wave.
    __syncthreads();  // all waves done reading staging before smem reuse
    float* Sf = (float*)smem + wid * (16 * 68);
#pragma unroll
    for (int fi = 0; fi < FM; fi++) {
#pragma unroll
      for (int fj = 0; fj < 4; fj++)
#pragma unroll
        for (int i = 0; i < 4; i++)
          Sf[(4 * lg + i) * 68 + fj * 16 + lr] = acc[fi][fj][i];
#pragma unroll
      for (int it = 0; it < 4; it++) {
        int rl = it * 4 + lg;
        f32x4 v = *(const f32x4*)&Sf[rl * 68 + lr * 4];
        int gm = m0 + wm + fi * 16 + rl;
        int gn = n0 + wn + lr * 4;
        float* op = (float*)outv + (size_t)gm * N + gn;
        if (gn + 3 < N) {
          *(f32x4*)op = v;
        } else {
#pragma unroll
          for (int j = 0; j < 4; j++)
            if (gn + j < N) op[j] = v[j];
        }
      }
    }
    return;
  }

#pragma unroll
  for (int fi = 0; fi < FM; fi++)
#pragma unroll
    for (int fj = 0; fj < FN; fj++) {
      int gn = n0 + wn + fj * 16 + lr;
      if (gn < N) {
        float bv = bias ? bias[gn] : 0.f;
#pragma unroll
        for (int i = 0; i < 4; i++) {
          int gm = m0 + wm + fi * 16 + 4 * lg + i;
          size_t o = (size_t)gm * N + gn;
          float v = acc[fi][fj][i] + bv;
          if (OUT == 0) {
            if (res) v += res[o];
            ((float*)outv)[o] = v;
          } else if (OUT == 1) {
            ((ushort*)outv)[o] = f2bf(v);
          } else if (OUT == 3) {
            if (gn < Csz) v *= 0.18033688f;  // 0.125 * log2(e): exp2-softmax pre-scale
            ((ushort*)outv)[o] = f2bf(v);
          } else {
            float u = 0.7978845608f * (v + 0.044715f * v * v * v);
            float t2 = __expf(2.f * u);
            float th = 1.f - 2.f / (t2 + 1.f);
            ((ushort*)outv)[o] = f2bf(0.5f * v * (1.f + th));
          }
        }
      }
    }
}

// ---------------- flash attention (causal), qkv bf16 -> y bf16 ----------------
// 1-D grid B*H*16 with bijective XCD chunk swizzle (K/V L2-resident per XCD).
// Longest-first q0 within chunk. 4 waves; wave = 16 q rows; KVBLK=128.
// Q pre-scaled by 0.125*log2e in the qkv GEMM epilogue (OUT=3); softmax uses
// FIXED max = 0 (exact: softmax is shift-invariant; scores bounded |S|<~45 so
// exp2 cannot overflow f32). p = single v_exp_f32.
// T14 async split: K/V global loads for tile t+1 issued into regs before QK^T(t).
__global__ __launch_bounds__(256) void k_attn(const ushort* __restrict__ qkv,
                                              ushort* __restrict__ ybf) {
  __shared__ __align__(16) ushort Ks[128 * 72];      // [k][d], 18.4 KB
  __shared__ __align__(16) ushort Vs[64 * 136];      // [d][k] transposed, 17.4 KB
  __shared__ __align__(16) ushort Ps[4 * 16 * 136];  // per-wave P rows, 17.4 KB
  int bid = blockIdx.x;
  bid = (bid & 7) * ((Bsz * Hsz * 16) >> 3) + (bid >> 3);  // XCD chunk swizzle
  int bh = bid >> 4;
  int q0 = (15 - (bid & 15)) * 64;  // longest-first within chunk
  int b = bh / Hsz, h = bh % Hsz;
  int tid = threadIdx.x, wid = tid >> 6, lane = tid & 63, lg = lane >> 4, lr = lane & 15;
  const ushort* base = qkv + (size_t)b * Tsz * 2304;

  int qt = q0 + wid * 16 + lr;
  const ushort* qp = base + (size_t)qt * 2304 + h * 64;
  short8 aq0 = *(const short8*)(qp + lg * 8);
  short8 aq1 = *(const short8*)(qp + 32 + lg * 8);

  int srow = tid >> 3, soff = (tid & 7) * 8;  // 4 chunks/thread: rows srow + r*32
  const ushort* kp0 = base + (size_t)srow * 2304 + 768 + h * 64 + soff;
  const ushort* vp0 = kp0 + 768;
  short8 kreg[4], vreg[4];
  auto LOADKV = [&](int k0) {
#pragma unroll
    for (int r = 0; r < 4; r++) {
      kreg[r] = *(const short8*)(kp0 + (size_t)(k0 + r * 32) * 2304);
      vreg[r] = *(const short8*)(vp0 + (size_t)(k0 + r * 32) * 2304);
    }
  };
  auto WRITEKV = [&]() {
#pragma unroll
    for (int r = 0; r < 4; r++) {
      int row = srow + r * 32;
      *(short8*)&Ks[row * 72 + soff] = kreg[r];
#pragma unroll
      for (int j = 0; j < 8; j++) Vs[(soff + j) * 136 + row] = (ushort)vreg[r][j];
    }
  };

  const f32x4 FZ = {0.f, 0.f, 0.f, 0.f};
  f32x4 of[4];
  of[0] = FZ; of[1] = FZ; of[2] = FZ; of[3] = FZ;
  float lrow[4] = {0.f, 0.f, 0.f, 0.f};

  int nkt = (q0 >> 7) + 1;  // tiles of 128 keys; rows < q0+64 <= nkt*128
  LOADKV(0);
  for (int kt = 0; kt < nkt; kt++) {
    int k0 = kt * 128;
    WRITEKV();
    __syncthreads();
    if (kt + 1 < nkt) LOADKV(k0 + 128);  // issue next tile's globals early

    // S = Q K^T : 16 rows x 128 keys per wave (S already includes 0.125*log2e)
    f32x4 sf[8];
#pragma unroll
    for (int nf = 0; nf < 8; nf++) {
      sf[nf] = FZ;
      short8 b0 = *(const short8*)&Ks[(nf * 16 + lr) * 72 + lg * 8];
      short8 b1 = *(const short8*)&Ks[(nf * 16 + lr) * 72 + 32 + lg * 8];
      sf[nf] = __builtin_amdgcn_mfma_f32_16x16x32_bf16(aq0, b0, sf[nf], 0, 0, 0);
      sf[nf] = __builtin_amdgcn_mfma_f32_16x16x32_bf16(aq1, b1, sf[nf], 0, 0, 0);
    }

    bool last = (kt == nkt - 1);
#pragma unroll
    for (int i = 0; i < 4; i++) {
      int qr = q0 + wid * 16 + 4 * lg + i;
      float rs = 0.f;
#pragma unroll
      for (int nf = 0; nf < 8; nf++) {
        float s = sf[nf][i];
        if (last && k0 + nf * 16 + lr > qr) s = -INFINITY;
        float pv = exp2f(s);  // single v_exp_f32
        rs += pv;
        Ps[(wid * 16 + 4 * lg + i) * 136 + nf * 16 + lr] = f2bf(pv);
      }
#pragma unroll
      for (int o = 1; o < 16; o <<= 1) rs += __shfl_xor(rs, o, 16);
      lrow[i] += rs;
    }
    // No barrier: Ps rows are wave-private (same-wave ds_write->ds_read ordered by
    // lgkmcnt); Ks/Vs stable since the post-WRITEKV barrier.

    short8 ap[4];
#pragma unroll
    for (int c = 0; c < 4; c++)
      ap[c] = *(const short8*)&Ps[(wid * 16 + lr) * 136 + c * 32 + lg * 8];
#pragma unroll
    for (int df = 0; df < 4; df++) {
#pragma unroll
      for (int c = 0; c < 4; c++) {
        short8 bv = *(const short8*)&Vs[(df * 16 + lr) * 136 + c * 32 + lg * 8];
        of[df] = __builtin_amdgcn_mfma_f32_16x16x32_bf16(ap[c], bv, of[df], 0, 0, 0);
      }
    }
    __syncthreads();  // all waves done with Ks/Vs before next WRITEKV
  }

  ushort* yp = ybf + (size_t)b * Tsz * Csz;
#pragma unroll
  for (int df = 0; df < 4; df++)
#pragma unroll
    for (int i = 0; i < 4; i++) {
      int qr = q0 + wid * 16 + 4 * lg + i;
      float v = of[df][i] / lrow[i];
      yp[(size_t)qr * Csz + h * 64 + df * 16 + lr] = f2bf(v);
    }
}

// ---------------- host ----------------
extern "C" void kernel_launch(void* const* d_in, const int* in_sizes, int n_in,
                              void* d_out, int out_size, void* d_ws, size_t ws_size,
                              hipStream_t stream) {
  (void)in_sizes; (void)n_in; (void)out_size;
  const int* idx      = (const int*)d_in[0];
  const float* wte    = (const float*)d_in[1];
  const float* wpe    = (const float*)d_in[2];
  const float* ln1_w  = (const float*)d_in[3];
  const float* ln1_b  = (const float*)d_in[4];
  const float* attn_w = (const float*)d_in[5];
  const float* attn_b = (const float*)d_in[6];
  const float* proj_w = (const float*)d_in[7];
  const float* proj_b = (const float*)d_in[8];
  const float* ln2_w  = (const float*)d_in[9];
  const float* ln2_b  = (const float*)d_in[10];
  const float* fc_w   = (const float*)d_in[11];
  const float* fc_b   = (const float*)d_in[12];
  const float* fc2_w  = (const float*)d_in[13];
  const float* fc2_b  = (const float*)d_in[14];
  const float* lnf_w  = (const float*)d_in[15];
  const float* lnf_b  = (const float*)d_in[16];
  const float* lm_w   = (const float*)d_in[17];
  float* out = (float*)d_out;

  char* ws = (char*)d_ws;
  float*  x     = (float*)(ws + 0);            // 2048*768*4   = 6291456
  ushort* qkvbf = (ushort*)(ws + 6291456);     // 2048*2304*2  = 9437184
  ushort* abuf  = (ushort*)(ws + 15728640);    // 2048*768*2   = 3145728
  ushort* hbuf  = (ushort*)(ws + 18874368);    // 2048*3072*2  = 12582912
  ushort* lmw   = (ushort*)(ws + 31457280);    // 50304*768*2  = 77266944
  ushort* wT    = (ushort*)(ws + 108724224);   // 12*C*C*2 per layer
  const size_t LSTRIDE = (size_t)12 * Csz * Csz;                 // elems per layer
  const size_t NEED_FULL = 108724224ull + LSTRIDE * 2 * Lsz;     // ~278.6 MB
  bool full = ws_size >= NEED_FULL;

  k_embed<<<Msz, 256, 0, stream>>>(idx, wte, wpe, x);
  k_f32_to_bf16_pad<<<4096, 256, 0, stream>>>(lm_w, lmw, Vsz * Csz, VPAD * Csz);
  if (full)
    k_prep<<<dim3(6912, Lsz), 256, 0, stream>>>(attn_w, proj_w, fc_w, fc2_w, wT, 0, LSTRIDE);

  for (int l = 0; l < Lsz; l++) {
    ushort* wTl = wT + (full ? (size_t)l * LSTRIDE : 0);
    if (!full)
      k_prep<<<dim3(6912, 1), 256, 0, stream>>>(attn_w, proj_w, fc_w, fc2_w, wTl, l, 0);
    const ushort* qkvW = wTl;
    const ushort* projW = wTl + (size_t)3 * Csz * Csz;
    const ushort* fcW   = wTl + (size_t)4 * Csz * Csz;
    const ushort* fc2W  = wTl + (size_t)8 * Csz * Csz;

    // --- attention ---
    k_ln<<<Msz / 4, 256, 0, stream>>>(x, ln1_w + l * Csz, ln1_b + l * Csz, abuf);
    k_gemm<128, 96, 4, 3, 64, 3, false, 0, true, 1><<<(Msz / 128) * (3 * Csz / 96), 256, 0, stream>>>(
        abuf, qkvW, attn_b + (size_t)l * 3 * Csz, nullptr, qkvbf, 3 * Csz, Csz, Msz / 128);
    k_attn<<<Bsz * Hsz * 16, 256, 0, stream>>>(qkvbf, abuf);
    k_gemm<64, 96, 2, 3, 64, 0, false, 0, true, 1><<<(Msz / 64) * (Csz / 96), 256, 0, stream>>>(
        abuf, projW, proj_b + (size_t)l * Csz, x, x, Csz, Csz, Msz / 64);
    // --- mlp ---
    k_ln<<<Msz / 4, 256, 0, stream>>>(x, ln2_w + l * Csz, ln2_b + l * Csz, abuf);
    k_gemm<128, 128, 4, 4, 64, 2, false, 0, true, 1><<<(Msz / 128) * (4 * Csz / 128), 256, 0, stream>>>(
        abuf, fcW, fc_b + (size_t)l * 4 * Csz, nullptr, hbuf, 4 * Csz, Csz, Msz / 128);
    k_gemm<64, 96, 2, 3, 64, 0, false, 0, true, 1><<<(Msz / 64) * (Csz / 96), 256, 0, stream>>>(
        hbuf, fc2W, fc2_b + (size_t)l * Csz, x, x, Csz, 4 * Csz, Msz / 64);
  }

  k_ln<<<Msz / 4, 256, 0, stream>>>(x, lnf_w, lnf_b, abuf);
  int ntm = Msz / 64;  // 32, m fastest
  // lm_head: R6-proven config — single-buffer, BK=64, 24.6 KB LDS, ~43-64% occ, ~2.4-2.55 TB/s
  k_gemm<64, 128, 2, 4, 64, 0, true, 0, false, 1><<<ntm * (VPAD / 128), 256, 0, stream>>>(
      abuf, lmw, nullptr, nullptr, out, Vsz, Csz, ntm);
}

// Round 19
// 2246.626 us; speedup vs baseline: 1.8163x; 1.0275x over previous
//
#include <hip/hip_runtime.h>
#include <hip/hip_bf16.h>

#define Bsz 2
#define Tsz 1024
#define Vsz 50257
#define Csz 768
#define Lsz 12
#define Hsz 12
#define Msz 2048  // B*T
#define VPAD 50304  // Vsz rounded up to 128

typedef __attribute__((ext_vector_type(8))) short short8;
typedef __attribute__((ext_vector_type(4))) float f32x4;

__device__ __forceinline__ ushort f2bf(float f) {
  union { float f; unsigned u; } v; v.f = f;
  return (ushort)((v.u + 0x7FFFu + ((v.u >> 16) & 1u)) >> 16);
}

__device__ __forceinline__ void load_lds16(const void* g, void* l) {
  __builtin_amdgcn_global_load_lds(
      (const __attribute__((address_space(1))) unsigned int*)g,
      (__attribute__((address_space(3))) unsigned int*)l, 16, 0, 0);
}

// ---------------- embedding ----------------
__global__ void k_embed(const int* __restrict__ idx, const float* __restrict__ wte,
                        const float* __restrict__ wpe, float* __restrict__ x) {
  int m = blockIdx.x;
  int t = m & (Tsz - 1);
  const float* src = wte + (size_t)idx[m] * Csz;
  const float* pe  = wpe + (size_t)t * Csz;
  float* dst = x + (size_t)m * Csz;
  for (int c = threadIdx.x; c < Csz; c += 256)
    dst[c] = src[c] + pe[c];
}

// ---------------- layernorm (f32 in -> bf16 out), 4 rows/block, wave-level ----------------
__global__ void k_ln(const float* __restrict__ x, const float* __restrict__ w,
                     const float* __restrict__ b, ushort* __restrict__ out) {
  int r = blockIdx.x * 4 + (threadIdx.x >> 6);
  int lane = threadIdx.x & 63;
  const float* row = x + (size_t)r * Csz;
  float v[12];
  float s = 0.f, q = 0.f;
#pragma unroll
  for (int j = 0; j < 12; j++) {
    v[j] = row[lane + j * 64];
    s += v[j];
    q += v[j] * v[j];
  }
#pragma unroll
  for (int o = 1; o < 64; o <<= 1) {
    s += __shfl_xor(s, o, 64);
    q += __shfl_xor(q, o, 64);
  }
  float mean = s * (1.0f / Csz);
  float rstd = rsqrtf(q * (1.0f / Csz) - mean * mean + 1e-5f);
  ushort* o = out + (size_t)r * Csz;
#pragma unroll
  for (int j = 0; j < 12; j++) {
    int c = lane + j * 64;
    o[c] = f2bf((v[j] - mean) * rstd * w[c] + b[c]);
  }
}

// ---------------- batched weight prep: transpose f32 [R][Cn] -> bf16 [Cn][R] ----------------
__global__ void k_prep(const float* __restrict__ aw, const float* __restrict__ pw,
                       const float* __restrict__ fw, const float* __restrict__ f2w,
                       ushort* __restrict__ wT, int l0, size_t lstride) {
  int t = blockIdx.x;
  int ly = l0 + blockIdx.y;
  const float* src; int R, Cn; size_t doff;
  if (t < 1728)      { src = aw  + (size_t)ly * Csz * 3 * Csz; R = Csz;     Cn = 3 * Csz; doff = 0; }
  else if (t < 2304) { t -= 1728; src = pw  + (size_t)ly * Csz * Csz;     R = Csz;     Cn = Csz;     doff = (size_t)3 * Csz * Csz; }
  else if (t < 4608) { t -= 2304; src = fw  + (size_t)ly * Csz * 4 * Csz; R = Csz;     Cn = 4 * Csz; doff = (size_t)4 * Csz * Csz; }
  else               { t -= 4608; src = f2w + (size_t)ly * 4 * Csz * Csz; R = 4 * Csz; Cn = Csz;     doff = (size_t)8 * Csz * Csz; }
  ushort* dst = wT + (size_t)blockIdx.y * lstride + doff;

  __shared__ float tb[32][33];
  int ncx = Cn / 32;
  int c0 = (t % ncx) * 32, r0 = (t / ncx) * 32;
  int tx = threadIdx.x & 31, ty = threadIdx.x >> 5;  // 32 x 8
#pragma unroll
  for (int k = 0; k < 4; k++)
    tb[ty + 8 * k][tx] = src[(size_t)(r0 + ty + 8 * k) * Cn + c0 + tx];
  __syncthreads();
#pragma unroll
  for (int k = 0; k < 4; k++)
    dst[(size_t)(c0 + ty + 8 * k) * R + r0 + tx] = f2bf(tb[tx][ty + 8 * k]);
}

// ---------------- f32 -> bf16 elementwise with zero-padded tail ----------------
__global__ void k_f32_to_bf16_pad(const float* __restrict__ src, ushort* __restrict__ dst,
                                  int n_src, int n_tot) {
  int stride = gridDim.x * 256 * 4;
  for (int i = (blockIdx.x * 256 + threadIdx.x) * 4; i < n_tot; i += stride) {
    ushort4 o;
    if (i + 3 < n_src) {
      float4 v = *(const float4*)(src + i);
      o.x = f2bf(v.x); o.y = f2bf(v.y); o.z = f2bf(v.z); o.w = f2bf(v.w);
    } else {
      o.x = o.y = o.z = o.w = 0;
    }
    *(ushort4*)(dst + i) = o;
  }
}

// ---------------- templated GEMM ----------------
// out[M][N] = A[M][K]bf16 @ Bt[N][K]bf16.
// OUT=0: f32 +bias +res; 1: bf16 +bias; 2: bf16 gelu(acc+bias);
// OUT=3: bf16 +bias, cols<768 scaled by 0.125*log2e (q pre-scale for exp2-softmax).
// outv must NOT alias A. 4 waves 2x2; wave tile (FM*16)x(FN*16).
// T2 swizzle on staging+reads. Loop modes:
//   PIPE=1: double-buffered, STAGE(t+1) before COMPUTE(t), K/BK even. BK=64 (fatter phases).
//   PIPE=0: single-buffer 2-barrier loop (BW-bound lm_head: best at ~43-64% occ, R6).
// Grid sizing: prefer total blocks ≡ 0 mod 256 (exact CU waves — avoids 1.5-wave tail).
// NOTE (R17 lesson): never fuse LN into A-staging (recomputed per n-tile; 2x regress).
// MINW = __launch_bounds__ min-waves-per-EU.
// BK=32 requires (BM+BN)%64==0; BK=64 requires (BM+BN)%32==0 (chunk map).
// EPI=1 (FN=4, bias/res null): FM-pass LDS-transpose epilogue -> f32x4 row stores.
template <int BM, int BN, int FM, int FN, int BK, int OUT, bool SWZ, int EPI, bool PIPE, int MINW>
__global__ __launch_bounds__(256, MINW) void k_gemm(
    const ushort* __restrict__ A, const ushort* __restrict__ Bt,
    const float* __restrict__ bias, const float* res,
    void* __restrict__ outv, int N, int K, int ntm) {
  constexpr int RPC = (BK == 64) ? 8 : 16;          // rows per 1KB chunk
  constexpr int NCHA = BM / RPC, NCH = (BM + BN) / RPC, CPW = NCH / 4;
  static_assert(NCH % 4 == 0, "chunk count must be divisible by wave count");
  constexpr int NBUF = PIPE ? 2 : 1;
  constexpr int STB = NBUF * (BM + BN) * BK * 2;    // staging bytes
  constexpr int EPB = EPI ? (4 * 16 * 68 * 4) : 0;  // epilogue bytes (per wave 16x68 f32)
  constexpr int SMB = STB > EPB ? STB : EPB;
  __shared__ __align__(16) char smem[SMB];

  int bid = blockIdx.x;
  if (SWZ) {
    int nwg = gridDim.x;
    bid = (bid & 7) * (nwg >> 3) + (bid >> 3);
  }
  int by = bid % ntm, bx = bid / ntm;
  int m0 = by * BM, n0 = bx * BN;

  int tid = threadIdx.x;
  int wid = tid >> 6, lane = tid & 63, lg = lane >> 4, lr = lane & 15;
  int wm = (wid >> 1) * (FM * 16), wn = (wid & 1) * (FN * 16);

  const f32x4 FZ = {0.f, 0.f, 0.f, 0.f};
  f32x4 acc[FM][FN];
#pragma unroll
  for (int i = 0; i < FM; i++)
#pragma unroll
    for (int j = 0; j < FN; j++) acc[i][j] = FZ;

  int srow, scol;
  if (BK == 64) { srow = lane >> 3; scol = ((lane & 7) ^ (srow & 7)) * 8; }
  else          { srow = lane >> 2; scol = ((lane & 3) ^ ((lane >> 3) & 3)) * 8; }

  const ushort* p[CPW];
  int ldso[CPW];
#pragma unroll
  for (int i = 0; i < CPW; i++) {
    int c = wid * CPW + i;
    ldso[i] = c * 512;
    if (c < NCHA) p[i] = A + (size_t)(m0 + c * RPC + srow) * K + scol;
    else          p[i] = Bt + (size_t)(n0 + (c - NCHA) * RPC + srow) * K + scol;
  }

  auto STAGE = [&](int buf) {
    ushort* Sb = (ushort*)smem + buf * (BM + BN) * BK;
#pragma unroll
    for (int i = 0; i < CPW; i++) {
      load_lds16(p[i], Sb + ldso[i]);
      p[i] += BK;
    }
  };
  auto COMPUTE = [&](int buf) {
    const ushort* Sb = (const ushort*)smem + buf * (BM + BN) * BK;
#pragma unroll
    for (int kk = 0; kk < BK / 32; kk++) {
      int cofs;
      if (BK == 64) cofs = (kk * 32 + lg * 8) ^ ((lr & 7) << 3);
      else          cofs = (lg * 8) ^ (((lr >> 1) & 3) << 3);
      short8 a[FM], b[FN];
#pragma unroll
      for (int f = 0; f < FM; f++)
        a[f] = *(const short8*)&Sb[(wm + f * 16 + lr) * BK + cofs];
#pragma unroll
      for (int f = 0; f < FN; f++)
        b[f] = *(const short8*)&Sb[(BM + wn + f * 16 + lr) * BK + cofs];
#pragma unroll
      for (int fi = 0; fi < FM; fi++)
#pragma unroll
        for (int fj = 0; fj < FN; fj++)
          acc[fi][fj] = __builtin_amdgcn_mfma_f32_16x16x32_bf16(a[fi], b[fj], acc[fi][fj], 0, 0, 0);
    }
  };

  if (PIPE) {
    int NT = K / BK;  // even by contract
    STAGE(0);
    __syncthreads();
    for (int t = 0;;) {
      if (t + 1 < NT) STAGE(1);
      COMPUTE(0);
      if (++t == NT) break;
      __syncthreads();  // drains STAGE(1); buf0 free
      if (t + 1 < NT) STAGE(0);
      COMPUTE(1);
      if (++t == NT) break;
      __syncthreads();  // drains STAGE(0); buf1 free
    }
  } else {
    int NT = K / BK;
    for (int t = 0; t < NT; t++) {
      STAGE(0);
      __syncthreads();  // vmcnt drained by compiler before barrier
      COMPUTE(0);
      __syncthreads();
    }
  }

  if constexpr (EPI) {
    // FM-pass LDS-transpose epilogue (FN=4): per pass one 16x64 f32 frag-row per wave.
    __syncthreads();  // all waves done reading staging before smem reuse
    float* Sf = (float*)smem + wid * (16 * 68);
#pragma unroll
    for (int fi = 0; fi < FM; fi++) {
#pragma unroll
      for (int fj = 0; fj < 4; fj++)
#pragma unroll
        for (int i = 0; i < 4; i++)
          Sf[(4 * lg + i) * 68 + fj * 16 + lr] = acc[fi][fj][i];
#pragma unroll
      for (int it = 0; it < 4; it++) {
        int rl = it * 4 + lg;
        f32x4 v = *(const f32x4*)&Sf[rl * 68 + lr * 4];
        int gm = m0 + wm + fi * 16 + rl;
        int gn = n0 + wn + lr * 4;
        float* op = (float*)outv + (size_t)gm * N + gn;
        if (gn + 3 < N) {
          *(f32x4*)op = v;
        } else {
#pragma unroll
          for (int j = 0; j < 4; j++)
            if (gn + j < N) op[j] = v[j];
        }
      }
    }
    return;
  }

#pragma unroll
  for (int fi = 0; fi < FM; fi++)
#pragma unroll
    for (int fj = 0; fj < FN; fj++) {
      int gn = n0 + wn + fj * 16 + lr;
      if (gn < N) {
        float bv = bias ? bias[gn] : 0.f;
#pragma unroll
        for (int i = 0; i < 4; i++) {
          int gm = m0 + wm + fi * 16 + 4 * lg + i;
          size_t o = (size_t)gm * N + gn;
          float v = acc[fi][fj][i] + bv;
          if (OUT == 0) {
            if (res) v += res[o];
            ((float*)outv)[o] = v;
          } else if (OUT == 1) {
            ((ushort*)outv)[o] = f2bf(v);
          } else if (OUT == 3) {
            if (gn < Csz) v *= 0.18033688f;  // 0.125 * log2(e): exp2-softmax pre-scale
            ((ushort*)outv)[o] = f2bf(v);
          } else {
            float u = 0.7978845608f * (v + 0.044715f * v * v * v);
            float t2 = __expf(2.f * u);
            float th = 1.f - 2.f / (t2 + 1.f);
            ((ushort*)outv)[o] = f2bf(0.5f * v * (1.f + th));
          }
        }
      }
    }
}

// ---------------- flash attention (causal), qkv bf16 -> y bf16 ----------------
// 1-D grid B*H*16 with bijective XCD chunk swizzle (K/V L2-resident per XCD).
// Longest-first q0 within chunk. 4 waves; wave = 16 q rows; KVBLK=128.
// Q pre-scaled by 0.125*log2e in the qkv GEMM epilogue (OUT=3); softmax uses
// FIXED max = 0 (exact: softmax is shift-invariant; scores bounded |S|<~45 so
// exp2 cannot overflow f32). p = single v_exp_f32.
// T14 async split: K/V global loads for tile t+1 issued into regs before QK^T(t).
__global__ __launch_bounds__(256) void k_attn(const ushort* __restrict__ qkv,
                                              ushort* __restrict__ ybf) {
  __shared__ __align__(16) ushort Ks[128 * 72];      // [k][d], 18.4 KB
  __shared__ __align__(16) ushort Vs[64 * 136];      // [d][k] transposed, 17.4 KB
  __shared__ __align__(16) ushort Ps[4 * 16 * 136];  // per-wave P rows, 17.4 KB
  int bid = blockIdx.x;
  bid = (bid & 7) * ((Bsz * Hsz * 16) >> 3) + (bid >> 3);  // XCD chunk swizzle
  int bh = bid >> 4;
  int q0 = (15 - (bid & 15)) * 64;  // longest-first within chunk
  int b = bh / Hsz, h = bh % Hsz;
  int tid = threadIdx.x, wid = tid >> 6, lane = tid & 63, lg = lane >> 4, lr = lane & 15;
  const ushort* base = qkv + (size_t)b * Tsz * 2304;

  int qt = q0 + wid * 16 + lr;
  const ushort* qp = base + (size_t)qt * 2304 + h * 64;
  short8 aq0 = *(const short8*)(qp + lg * 8);
  short8 aq1 = *(const short8*)(qp + 32 + lg * 8);

  int srow = tid >> 3, soff = (tid & 7) * 8;  // 4 chunks/thread: rows srow + r*32
  const ushort* kp0 = base + (size_t)srow * 2304 + 768 + h * 64 + soff;
  const ushort* vp0 = kp0 + 768;
  short8 kreg[4], vreg[4];
  auto LOADKV = [&](int k0) {
#pragma unroll
    for (int r = 0; r < 4; r++) {
      kreg[r] = *(const short8*)(kp0 + (size_t)(k0 + r * 32) * 2304);
      vreg[r] = *(const short8*)(vp0 + (size_t)(k0 + r * 32) * 2304);
    }
  };
  auto WRITEKV = [&]() {
#pragma unroll
    for (int r = 0; r < 4; r++) {
      int row = srow + r * 32;
      *(short8*)&Ks[row * 72 + soff] = kreg[r];
#pragma unroll
      for (int j = 0; j < 8; j++) Vs[(soff + j) * 136 + row] = (ushort)vreg[r][j];
    }
  };

  const f32x4 FZ = {0.f, 0.f, 0.f, 0.f};
  f32x4 of[4];
  of[0] = FZ; of[1] = FZ; of[2] = FZ; of[3] = FZ;
  float lrow[4] = {0.f, 0.f, 0.f, 0.f};

  int nkt = (q0 >> 7) + 1;  // tiles of 128 keys; rows < q0+64 <= nkt*128
  LOADKV(0);
  for (int kt = 0; kt < nkt; kt++) {
    int k0 = kt * 128;
    WRITEKV();
    __syncthreads();
    if (kt + 1 < nkt) LOADKV(k0 + 128);  // issue next tile's globals early

    // S = Q K^T : 16 rows x 128 keys per wave (S already includes 0.125*log2e)
    f32x4 sf[8];
#pragma unroll
    for (int nf = 0; nf < 8; nf++) {
      sf[nf] = FZ;
      short8 b0 = *(const short8*)&Ks[(nf * 16 + lr) * 72 + lg * 8];
      short8 b1 = *(const short8*)&Ks[(nf * 16 + lr) * 72 + 32 + lg * 8];
      sf[nf] = __builtin_amdgcn_mfma_f32_16x16x32_bf16(aq0, b0, sf[nf], 0, 0, 0);
      sf[nf] = __builtin_amdgcn_mfma_f32_16x16x32_bf16(aq1, b1, sf[nf], 0, 0, 0);
    }

    bool last = (kt == nkt - 1);
#pragma unroll
    for (int i = 0; i < 4; i++) {
      int qr = q0 + wid * 16 + 4 * lg + i;
      float rs = 0.f;
#pragma unroll
      for (int nf = 0; nf < 8; nf++) {
        float s = sf[nf][i];
        if (last && k0 + nf * 16 + lr > qr) s = -INFINITY;
        float pv = exp2f(s);  // single v_exp_f32
        rs += pv;
        Ps[(wid * 16 + 4 * lg + i) * 136 + nf * 16 + lr] = f2bf(pv);
      }
#pragma unroll
      for (int o = 1; o < 16; o <<= 1) rs += __shfl_xor(rs, o, 16);
      lrow[i] += rs;
    }
    // No barrier: Ps rows are wave-private (same-wave ds_write->ds_read ordered by
    // lgkmcnt); Ks/Vs stable since the post-WRITEKV barrier.

    short8 ap[4];
#pragma unroll
    for (int c = 0; c < 4; c++)
      ap[c] = *(const short8*)&Ps[(wid * 16 + lr) * 136 + c * 32 + lg * 8];
#pragma unroll
    for (int df = 0; df < 4; df++) {
#pragma unroll
      for (int c = 0; c < 4; c++) {
        short8 bv = *(const short8*)&Vs[(df * 16 + lr) * 136 + c * 32 + lg * 8];
        of[df] = __builtin_amdgcn_mfma_f32_16x16x32_bf16(ap[c], bv, of[df], 0, 0, 0);
      }
    }
    __syncthreads();  // all waves done with Ks/Vs before next WRITEKV
  }

  ushort* yp = ybf + (size_t)b * Tsz * Csz;
#pragma unroll
  for (int df = 0; df < 4; df++)
#pragma unroll
    for (int i = 0; i < 4; i++) {
      int qr = q0 + wid * 16 + 4 * lg + i;
      float v = of[df][i] / lrow[i];
      yp[(size_t)qr * Csz + h * 64 + df * 16 + lr] = f2bf(v);
    }
}

// ---------------- host ----------------
extern "C" void kernel_launch(void* const* d_in, const int* in_sizes, int n_in,
                              void* d_out, int out_size, void* d_ws, size_t ws_size,
                              hipStream_t stream) {
  (void)in_sizes; (void)n_in; (void)out_size;
  const int* idx      = (const int*)d_in[0];
  const float* wte    = (const float*)d_in[1];
  const float* wpe    = (const float*)d_in[2];
  const float* ln1_w  = (const float*)d_in[3];
  const float* ln1_b  = (const float*)d_in[4];
  const float* attn_w = (const float*)d_in[5];
  const float* attn_b = (const float*)d_in[6];
  const float* proj_w = (const float*)d_in[7];
  const float* proj_b = (const float*)d_in[8];
  const float* ln2_w  = (const float*)d_in[9];
  const float* ln2_b  = (const float*)d_in[10];
  const float* fc_w   = (const float*)d_in[11];
  const float* fc_b   = (const float*)d_in[12];
  const float* fc2_w  = (const float*)d_in[13];
  const float* fc2_b  = (const float*)d_in[14];
  const float* lnf_w  = (const float*)d_in[15];
  const float* lnf_b  = (const float*)d_in[16];
  const float* lm_w   = (const float*)d_in[17];
  float* out = (float*)d_out;

  char* ws = (char*)d_ws;
  float*  x     = (float*)(ws + 0);            // 2048*768*4   = 6291456
  ushort* qkvbf = (ushort*)(ws + 6291456);     // 2048*2304*2  = 9437184
  ushort* abuf  = (ushort*)(ws + 15728640);    // 2048*768*2   = 3145728
  ushort* hbuf  = (ushort*)(ws + 18874368);    // 2048*3072*2  = 12582912
  ushort* lmw   = (ushort*)(ws + 31457280);    // 50304*768*2  = 77266944
  ushort* wT    = (ushort*)(ws + 108724224);   // 12*C*C*2 per layer
  const size_t LSTRIDE = (size_t)12 * Csz * Csz;                 // elems per layer
  const size_t NEED_FULL = 108724224ull + LSTRIDE * 2 * Lsz;     // ~278.6 MB
  bool full = ws_size >= NEED_FULL;

  k_embed<<<Msz, 256, 0, stream>>>(idx, wte, wpe, x);
  k_f32_to_bf16_pad<<<4096, 256, 0, stream>>>(lm_w, lmw, Vsz * Csz, VPAD * Csz);
  if (full)
    k_prep<<<dim3(6912, Lsz), 256, 0, stream>>>(attn_w, proj_w, fc_w, fc2_w, wT, 0, LSTRIDE);

  for (int l = 0; l < Lsz; l++) {
    ushort* wTl = wT + (full ? (size_t)l * LSTRIDE : 0);
    if (!full)
      k_prep<<<dim3(6912, 1), 256, 0, stream>>>(attn_w, proj_w, fc_w, fc2_w, wTl, l, 0);
    const ushort* qkvW = wTl;
    const ushort* projW = wTl + (size_t)3 * Csz * Csz;
    const ushort* fcW   = wTl + (size_t)4 * Csz * Csz;
    const ushort* fc2W  = wTl + (size_t)8 * Csz * Csz;

    // --- attention ---
    k_ln<<<Msz / 4, 256, 0, stream>>>(x, ln1_w + l * Csz, ln1_b + l * Csz, abuf);
    // qkv: 64x96 -> grid 768 = 3.0 CU-waves (no tail)
    k_gemm<64, 96, 2, 3, 64, 3, false, 0, true, 1><<<(Msz / 64) * (3 * Csz / 96), 256, 0, stream>>>(
        abuf, qkvW, attn_b + (size_t)l * 3 * Csz, nullptr, qkvbf, 3 * Csz, Csz, Msz / 64);
    k_attn<<<Bsz * Hsz * 16, 256, 0, stream>>>(qkvbf, abuf);
    k_gemm<64, 96, 2, 3, 64, 0, false, 0, true, 1><<<(Msz / 64) * (Csz / 96), 256, 0, stream>>>(
        abuf, projW, proj_b + (size_t)l * Csz, x, x, Csz, Csz, Msz / 64);
    // --- mlp ---
    k_ln<<<Msz / 4, 256, 0, stream>>>(x, ln2_w + l * Csz, ln2_b + l * Csz, abuf);
    // fc: 64x128 -> grid 768 = 3.0 CU-waves (no tail)
    k_gemm<64, 128, 2, 4, 64, 2, false, 0, true, 1><<<(Msz / 64) * (4 * Csz / 128), 256, 0, stream>>>(
        abuf, fcW, fc_b + (size_t)l * 4 * Csz, nullptr, hbuf, 4 * Csz, Csz, Msz / 64);
    k_gemm<64, 96, 2, 3, 64, 0, false, 0, true, 1><<<(Msz / 64) * (Csz / 96), 256, 0, stream>>>(
        hbuf, fc2W, fc2_b + (size_t)l * Csz, x, x, Csz, 4 * Csz, Msz / 64);
  }

  k_ln<<<Msz / 4, 256, 0, stream>>>(x, lnf_w, lnf_b, abuf);
  int ntm = Msz / 64;  // 32, m fastest
  // lm_head: R6-proven config — single-buffer, BK=64, 24.6 KB LDS, ~43-64% occ, ~2.4-2.55 TB/s
  k_gemm<64, 128, 2, 4, 64, 0, true, 0, false, 1><<<ntm * (VPAD / 128), 256, 0, stream>>>(
      abuf, lmw, nullptr, nullptr, out, Vsz, Csz, ntm);
}

// Round 20
// 2131.821 us; speedup vs baseline: 1.9141x; 1.0539x over previous
//
#include <hip/hip_runtime.h>
#include <hip/hip_bf16.h>

#define Bsz 2
#define Tsz 1024
#define Vsz 50257
#define Csz 768
#define Lsz 12
#define Hsz 12
#define Msz 2048  // B*T
#define VPAD 50304  // Vsz rounded up to 128

typedef __attribute__((ext_vector_type(8))) short short8;
typedef __attribute__((ext_vector_type(4))) float f32x4;

__device__ __forceinline__ ushort f2bf(float f) {
  union { float f; unsigned u; } v; v.f = f;
  return (ushort)((v.u + 0x7FFFu + ((v.u >> 16) & 1u)) >> 16);
}

__device__ __forceinline__ void load_lds16(const void* g, void* l) {
  __builtin_amdgcn_global_load_lds(
      (const __attribute__((address_space(1))) unsigned int*)g,
      (__attribute__((address_space(3))) unsigned int*)l, 16, 0, 0);
}

// ---------------- embedding ----------------
__global__ void k_embed(const int* __restrict__ idx, const float* __restrict__ wte,
                        const float* __restrict__ wpe, float* __restrict__ x) {
  int m = blockIdx.x;
  int t = m & (Tsz - 1);
  const float* src = wte + (size_t)idx[m] * Csz;
  const float* pe  = wpe + (size_t)t * Csz;
  float* dst = x + (size_t)m * Csz;
  for (int c = threadIdx.x; c < Csz; c += 256)
    dst[c] = src[c] + pe[c];
}

// ---------------- layernorm (f32 in -> bf16 out), 4 rows/block, wave-level ----------------
__global__ void k_ln(const float* __restrict__ x, const float* __restrict__ w,
                     const float* __restrict__ b, ushort* __restrict__ out) {
  int r = blockIdx.x * 4 + (threadIdx.x >> 6);
  int lane = threadIdx.x & 63;
  const float* row = x + (size_t)r * Csz;
  float v[12];
  float s = 0.f, q = 0.f;
#pragma unroll
  for (int j = 0; j < 12; j++) {
    v[j] = row[lane + j * 64];
    s += v[j];
    q += v[j] * v[j];
  }
#pragma unroll
  for (int o = 1; o < 64; o <<= 1) {
    s += __shfl_xor(s, o, 64);
    q += __shfl_xor(q, o, 64);
  }
  float mean = s * (1.0f / Csz);
  float rstd = rsqrtf(q * (1.0f / Csz) - mean * mean + 1e-5f);
  ushort* o = out + (size_t)r * Csz;
#pragma unroll
  for (int j = 0; j < 12; j++) {
    int c = lane + j * 64;
    o[c] = f2bf((v[j] - mean) * rstd * w[c] + b[c]);
  }
}

// ---------------- batched weight prep: transpose f32 [R][Cn] -> bf16 [Cn][R] ----------------
__global__ void k_prep(const float* __restrict__ aw, const float* __restrict__ pw,
                       const float* __restrict__ fw, const float* __restrict__ f2w,
                       ushort* __restrict__ wT, int l0, size_t lstride) {
  int t = blockIdx.x;
  int ly = l0 + blockIdx.y;
  const float* src; int R, Cn; size_t doff;
  if (t < 1728)      { src = aw  + (size_t)ly * Csz * 3 * Csz; R = Csz;     Cn = 3 * Csz; doff = 0; }
  else if (t < 2304) { t -= 1728; src = pw  + (size_t)ly * Csz * Csz;     R = Csz;     Cn = Csz;     doff = (size_t)3 * Csz * Csz; }
  else if (t < 4608) { t -= 2304; src = fw  + (size_t)ly * Csz * 4 * Csz; R = Csz;     Cn = 4 * Csz; doff = (size_t)4 * Csz * Csz; }
  else               { t -= 4608; src = f2w + (size_t)ly * 4 * Csz * Csz; R = 4 * Csz; Cn = Csz;     doff = (size_t)8 * Csz * Csz; }
  ushort* dst = wT + (size_t)blockIdx.y * lstride + doff;

  __shared__ float tb[32][33];
  int ncx = Cn / 32;
  int c0 = (t % ncx) * 32, r0 = (t / ncx) * 32;
  int tx = threadIdx.x & 31, ty = threadIdx.x >> 5;  // 32 x 8
#pragma unroll
  for (int k = 0; k < 4; k++)
    tb[ty + 8 * k][tx] = src[(size_t)(r0 + ty + 8 * k) * Cn + c0 + tx];
  __syncthreads();
#pragma unroll
  for (int k = 0; k < 4; k++)
    dst[(size_t)(c0 + ty + 8 * k) * R + r0 + tx] = f2bf(tb[tx][ty + 8 * k]);
}

// ---------------- f32 -> bf16 elementwise with zero-padded tail ----------------
__global__ void k_f32_to_bf16_pad(const float* __restrict__ src, ushort* __restrict__ dst,
                                  int n_src, int n_tot) {
  int stride = gridDim.x * 256 * 4;
  for (int i = (blockIdx.x * 256 + threadIdx.x) * 4; i < n_tot; i += stride) {
    ushort4 o;
    if (i + 3 < n_src) {
      float4 v = *(const float4*)(src + i);
      o.x = f2bf(v.x); o.y = f2bf(v.y); o.z = f2bf(v.z); o.w = f2bf(v.w);
    } else {
      o.x = o.y = o.z = o.w = 0;
    }
    *(ushort4*)(dst + i) = o;
  }
}

// ---------------- templated GEMM ----------------
// out[M][N] = A[M][K]bf16 @ Bt[N][K]bf16.
// OUT=0: f32 +bias +res; 1: bf16 +bias; 2: bf16 gelu(acc+bias);
// OUT=3: bf16 +bias, cols<768 scaled by 0.125*log2e (q pre-scale for exp2-softmax).
// outv must NOT alias A. 4 waves 2x2; wave tile (FM*16)x(FN*16).
// T2 swizzle on staging+reads. Loop modes:
//   PIPE=1: double-buffered, STAGE(t+1) before COMPUTE(t), K/BK even. BK=64 (fatter phases).
//   PIPE=0: single-buffer 2-barrier loop (BW-bound lm_head: best at ~43-64% occ, R6).
// Grid sizing: total blocks ≡ 0 mod 256 (exact CU waves) AND ≥2 blocks/CU where possible
// (1 block/CU has zero cross-block latency hiding — R20).
// NOTE (R17 lesson): never fuse LN into A-staging (recomputed per n-tile; 2x regress).
// MINW = __launch_bounds__ min-waves-per-EU.
// BK=32 requires (BM+BN)%64==0; BK=64 requires (BM+BN)%32==0 (chunk map).
// EPI=1 (FN=4, bias/res null): FM-pass LDS-transpose epilogue -> f32x4 row stores.
template <int BM, int BN, int FM, int FN, int BK, int OUT, bool SWZ, int EPI, bool PIPE, int MINW>
__global__ __launch_bounds__(256, MINW) void k_gemm(
    const ushort* __restrict__ A, const ushort* __restrict__ Bt,
    const float* __restrict__ bias, const float* res,
    void* __restrict__ outv, int N, int K, int ntm) {
  constexpr int RPC = (BK == 64) ? 8 : 16;          // rows per 1KB chunk
  constexpr int NCHA = BM / RPC, NCH = (BM + BN) / RPC, CPW = NCH / 4;
  static_assert(NCH % 4 == 0, "chunk count must be divisible by wave count");
  constexpr int NBUF = PIPE ? 2 : 1;
  constexpr int STB = NBUF * (BM + BN) * BK * 2;    // staging bytes
  constexpr int EPB = EPI ? (4 * 16 * 68 * 4) : 0;  // epilogue bytes (per wave 16x68 f32)
  constexpr int SMB = STB > EPB ? STB : EPB;
  __shared__ __align__(16) char smem[SMB];

  int bid = blockIdx.x;
  if (SWZ) {
    int nwg = gridDim.x;
    bid = (bid & 7) * (nwg >> 3) + (bid >> 3);
  }
  int by = bid % ntm, bx = bid / ntm;
  int m0 = by * BM, n0 = bx * BN;

  int tid = threadIdx.x;
  int wid = tid >> 6, lane = tid & 63, lg = lane >> 4, lr = lane & 15;
  int wm = (wid >> 1) * (FM * 16), wn = (wid & 1) * (FN * 16);

  const f32x4 FZ = {0.f, 0.f, 0.f, 0.f};
  f32x4 acc[FM][FN];
#pragma unroll
  for (int i = 0; i < FM; i++)
#pragma unroll
    for (int j = 0; j < FN; j++) acc[i][j] = FZ;

  int srow, scol;
  if (BK == 64) { srow = lane >> 3; scol = ((lane & 7) ^ (srow & 7)) * 8; }
  else          { srow = lane >> 2; scol = ((lane & 3) ^ ((lane >> 3) & 3)) * 8; }

  const ushort* p[CPW];
  int ldso[CPW];
#pragma unroll
  for (int i = 0; i < CPW; i++) {
    int c = wid * CPW + i;
    ldso[i] = c * 512;
    if (c < NCHA) p[i] = A + (size_t)(m0 + c * RPC + srow) * K + scol;
    else          p[i] = Bt + (size_t)(n0 + (c - NCHA) * RPC + srow) * K + scol;
  }

  auto STAGE = [&](int buf) {
    ushort* Sb = (ushort*)smem + buf * (BM + BN) * BK;
#pragma unroll
    for (int i = 0; i < CPW; i++) {
      load_lds16(p[i], Sb + ldso[i]);
      p[i] += BK;
    }
  };
  auto COMPUTE = [&](int buf) {
    const ushort* Sb = (const ushort*)smem + buf * (BM + BN) * BK;
#pragma unroll
    for (int kk = 0; kk < BK / 32; kk++) {
      int cofs;
      if (BK == 64) cofs = (kk * 32 + lg * 8) ^ ((lr & 7) << 3);
      else          cofs = (lg * 8) ^ (((lr >> 1) & 3) << 3);
      short8 a[FM], b[FN];
#pragma unroll
      for (int f = 0; f < FM; f++)
        a[f] = *(const short8*)&Sb[(wm + f * 16 + lr) * BK + cofs];
#pragma unroll
      for (int f = 0; f < FN; f++)
        b[f] = *(const short8*)&Sb[(BM + wn + f * 16 + lr) * BK + cofs];
#pragma unroll
      for (int fi = 0; fi < FM; fi++)
#pragma unroll
        for (int fj = 0; fj < FN; fj++)
          acc[fi][fj] = __builtin_amdgcn_mfma_f32_16x16x32_bf16(a[fi], b[fj], acc[fi][fj], 0, 0, 0);
    }
  };

  if (PIPE) {
    int NT = K / BK;  // even by contract
    STAGE(0);
    __syncthreads();
    for (int t = 0;;) {
      if (t + 1 < NT) STAGE(1);
      COMPUTE(0);
      if (++t == NT) break;
      __syncthreads();  // drains STAGE(1); buf0 free
      if (t + 1 < NT) STAGE(0);
      COMPUTE(1);
      if (++t == NT) break;
      __syncthreads();  // drains STAGE(0); buf1 free
    }
  } else {
    int NT = K / BK;
    for (int t = 0; t < NT; t++) {
      STAGE(0);
      __syncthreads();  // vmcnt drained by compiler before barrier
      COMPUTE(0);
      __syncthreads();
    }
  }

  if constexpr (EPI) {
    // FM-pass LDS-transpose epilogue (FN=4): per pass one 16x64 f32 frag-row per wave.
    __syncthreads();  // all waves done reading staging before smem reuse
    float* Sf = (float*)smem + wid * (16 * 68);
#pragma unroll
    for (int fi = 0; fi < FM; fi++) {
#pragma unroll
      for (int fj = 0; fj < 4; fj++)
#pragma unroll
        for (int i = 0; i < 4; i++)
          Sf[(4 * lg + i) * 68 + fj * 16 + lr] = acc[fi][fj][i];
#pragma unroll
      for (int it = 0; it < 4; it++) {
        int rl = it * 4 + lg;
        f32x4 v = *(const f32x4*)&Sf[rl * 68 + lr * 4];
        int gm = m0 + wm + fi * 16 + rl;
        int gn = n0 + wn + lr * 4;
        float* op = (float*)outv + (size_t)gm * N + gn;
        if (gn + 3 < N) {
          *(f32x4*)op = v;
        } else {
#pragma unroll
          for (int j = 0; j < 4; j++)
            if (gn + j < N) op[j] = v[j];
        }
      }
    }
    return;
  }

#pragma unroll
  for (int fi = 0; fi < FM; fi++)
#pragma unroll
    for (int fj = 0; fj < FN; fj++) {
      int gn = n0 + wn + fj * 16 + lr;
      if (gn < N) {
        float bv = bias ? bias[gn] : 0.f;
#pragma unroll
        for (int i = 0; i < 4; i++) {
          int gm = m0 + wm + fi * 16 + 4 * lg + i;
          size_t o = (size_t)gm * N + gn;
          float v = acc[fi][fj][i] + bv;
          if (OUT == 0) {
            if (res) v += res[o];
            ((float*)outv)[o] = v;
          } else if (OUT == 1) {
            ((ushort*)outv)[o] = f2bf(v);
          } else if (OUT == 3) {
            if (gn < Csz) v *= 0.18033688f;  // 0.125 * log2(e): exp2-softmax pre-scale
            ((ushort*)outv)[o] = f2bf(v);
          } else {
            float u = 0.7978845608f * (v + 0.044715f * v * v * v);
            float t2 = __expf(2.f * u);
            float th = 1.f - 2.f / (t2 + 1.f);
            ((ushort*)outv)[o] = f2bf(0.5f * v * (1.f + th));
          }
        }
      }
    }
}

// ---------------- flash attention (causal), qkv bf16 -> y bf16 ----------------
// 1-D grid B*H*16 with bijective XCD chunk swizzle (K/V L2-resident per XCD).
// Longest-first q0 within chunk. 4 waves; wave = 16 q rows; KVBLK=128.
// Q pre-scaled by 0.125*log2e in the qkv GEMM epilogue (OUT=3); softmax uses
// FIXED max = 0 (exact: softmax is shift-invariant; scores bounded |S|<~45 so
// exp2 cannot overflow f32). p = single v_exp_f32.
// T14 async split: K/V global loads for tile t+1 issued into regs before QK^T(t).
__global__ __launch_bounds__(256) void k_attn(const ushort* __restrict__ qkv,
                                              ushort* __restrict__ ybf) {
  __shared__ __align__(16) ushort Ks[128 * 72];      // [k][d], 18.4 KB
  __shared__ __align__(16) ushort Vs[64 * 136];      // [d][k] transposed, 17.4 KB
  __shared__ __align__(16) ushort Ps[4 * 16 * 136];  // per-wave P rows, 17.4 KB
  int bid = blockIdx.x;
  bid = (bid & 7) * ((Bsz * Hsz * 16) >> 3) + (bid >> 3);  // XCD chunk swizzle
  int bh = bid >> 4;
  int q0 = (15 - (bid & 15)) * 64;  // longest-first within chunk
  int b = bh / Hsz, h = bh % Hsz;
  int tid = threadIdx.x, wid = tid >> 6, lane = tid & 63, lg = lane >> 4, lr = lane & 15;
  const ushort* base = qkv + (size_t)b * Tsz * 2304;

  int qt = q0 + wid * 16 + lr;
  const ushort* qp = base + (size_t)qt * 2304 + h * 64;
  short8 aq0 = *(const short8*)(qp + lg * 8);
  short8 aq1 = *(const short8*)(qp + 32 + lg * 8);

  int srow = tid >> 3, soff = (tid & 7) * 8;  // 4 chunks/thread: rows srow + r*32
  const ushort* kp0 = base + (size_t)srow * 2304 + 768 + h * 64 + soff;
  const ushort* vp0 = kp0 + 768;
  short8 kreg[4], vreg[4];
  auto LOADKV = [&](int k0) {
#pragma unroll
    for (int r = 0; r < 4; r++) {
      kreg[r] = *(const short8*)(kp0 + (size_t)(k0 + r * 32) * 2304);
      vreg[r] = *(const short8*)(vp0 + (size_t)(k0 + r * 32) * 2304);
    }
  };
  auto WRITEKV = [&]() {
#pragma unroll
    for (int r = 0; r < 4; r++) {
      int row = srow + r * 32;
      *(short8*)&Ks[row * 72 + soff] = kreg[r];
#pragma unroll
      for (int j = 0; j < 8; j++) Vs[(soff + j) * 136 + row] = (ushort)vreg[r][j];
    }
  };

  const f32x4 FZ = {0.f, 0.f, 0.f, 0.f};
  f32x4 of[4];
  of[0] = FZ; of[1] = FZ; of[2] = FZ; of[3] = FZ;
  float lrow[4] = {0.f, 0.f, 0.f, 0.f};

  int nkt = (q0 >> 7) + 1;  // tiles of 128 keys; rows < q0+64 <= nkt*128
  LOADKV(0);
  for (int kt = 0; kt < nkt; kt++) {
    int k0 = kt * 128;
    WRITEKV();
    __syncthreads();
    if (kt + 1 < nkt) LOADKV(k0 + 128);  // issue next tile's globals early

    // S = Q K^T : 16 rows x 128 keys per wave (S already includes 0.125*log2e)
    f32x4 sf[8];
#pragma unroll
    for (int nf = 0; nf < 8; nf++) {
      sf[nf] = FZ;
      short8 b0 = *(const short8*)&Ks[(nf * 16 + lr) * 72 + lg * 8];
      short8 b1 = *(const short8*)&Ks[(nf * 16 + lr) * 72 + 32 + lg * 8];
      sf[nf] = __builtin_amdgcn_mfma_f32_16x16x32_bf16(aq0, b0, sf[nf], 0, 0, 0);
      sf[nf] = __builtin_amdgcn_mfma_f32_16x16x32_bf16(aq1, b1, sf[nf], 0, 0, 0);
    }

    bool last = (kt == nkt - 1);
#pragma unroll
    for (int i = 0; i < 4; i++) {
      int qr = q0 + wid * 16 + 4 * lg + i;
      float rs = 0.f;
#pragma unroll
      for (int nf = 0; nf < 8; nf++) {
        float s = sf[nf][i];
        if (last && k0 + nf * 16 + lr > qr) s = -INFINITY;
        float pv = exp2f(s);  // single v_exp_f32
        rs += pv;
        Ps[(wid * 16 + 4 * lg + i) * 136 + nf * 16 + lr] = f2bf(pv);
      }
#pragma unroll
      for (int o = 1; o < 16; o <<= 1) rs += __shfl_xor(rs, o, 16);
      lrow[i] += rs;
    }
    // No barrier: Ps rows are wave-private (same-wave ds_write->ds_read ordered by
    // lgkmcnt); Ks/Vs stable since the post-WRITEKV barrier.

    short8 ap[4];
#pragma unroll
    for (int c = 0; c < 4; c++)
      ap[c] = *(const short8*)&Ps[(wid * 16 + lr) * 136 + c * 32 + lg * 8];
#pragma unroll
    for (int df = 0; df < 4; df++) {
#pragma unroll
      for (int c = 0; c < 4; c++) {
        short8 bv = *(const short8*)&Vs[(df * 16 + lr) * 136 + c * 32 + lg * 8];
        of[df] = __builtin_amdgcn_mfma_f32_16x16x32_bf16(ap[c], bv, of[df], 0, 0, 0);
      }
    }
    __syncthreads();  // all waves done with Ks/Vs before next WRITEKV
  }

  ushort* yp = ybf + (size_t)b * Tsz * Csz;
#pragma unroll
  for (int df = 0; df < 4; df++)
#pragma unroll
    for (int i = 0; i < 4; i++) {
      int qr = q0 + wid * 16 + 4 * lg + i;
      float v = of[df][i] / lrow[i];
      yp[(size_t)qr * Csz + h * 64 + df * 16 + lr] = f2bf(v);
    }
}

// ---------------- host ----------------
extern "C" void kernel_launch(void* const* d_in, const int* in_sizes, int n_in,
                              void* d_out, int out_size, void* d_ws, size_t ws_size,
                              hipStream_t stream) {
  (void)in_sizes; (void)n_in; (void)out_size;
  const int* idx      = (const int*)d_in[0];
  const float* wte    = (const float*)d_in[1];
  const float* wpe    = (const float*)d_in[2];
  const float* ln1_w  = (const float*)d_in[3];
  const float* ln1_b  = (const float*)d_in[4];
  const float* attn_w = (const float*)d_in[5];
  const float* attn_b = (const float*)d_in[6];
  const float* proj_w = (const float*)d_in[7];
  const float* proj_b = (const float*)d_in[8];
  const float* ln2_w  = (const float*)d_in[9];
  const float* ln2_b  = (const float*)d_in[10];
  const float* fc_w   = (const float*)d_in[11];
  const float* fc_b   = (const float*)d_in[12];
  const float* fc2_w  = (const float*)d_in[13];
  const float* fc2_b  = (const float*)d_in[14];
  const float* lnf_w  = (const float*)d_in[15];
  const float* lnf_b  = (const float*)d_in[16];
  const float* lm_w   = (const float*)d_in[17];
  float* out = (float*)d_out;

  char* ws = (char*)d_ws;
  float*  x     = (float*)(ws + 0);            // 2048*768*4   = 6291456
  ushort* qkvbf = (ushort*)(ws + 6291456);     // 2048*2304*2  = 9437184
  ushort* abuf  = (ushort*)(ws + 15728640);    // 2048*768*2   = 3145728
  ushort* hbuf  = (ushort*)(ws + 18874368);    // 2048*3072*2  = 12582912
  ushort* lmw   = (ushort*)(ws + 31457280);    // 50304*768*2  = 77266944
  ushort* wT    = (ushort*)(ws + 108724224);   // 12*C*C*2 per layer
  const size_t LSTRIDE = (size_t)12 * Csz * Csz;                 // elems per layer
  const size_t NEED_FULL = 108724224ull + LSTRIDE * 2 * Lsz;     // ~278.6 MB
  bool full = ws_size >= NEED_FULL;

  k_embed<<<Msz, 256, 0, stream>>>(idx, wte, wpe, x);
  k_f32_to_bf16_pad<<<4096, 256, 0, stream>>>(lm_w, lmw, Vsz * Csz, VPAD * Csz);
  if (full)
    k_prep<<<dim3(6912, Lsz), 256, 0, stream>>>(attn_w, proj_w, fc_w, fc2_w, wT, 0, LSTRIDE);

  for (int l = 0; l < Lsz; l++) {
    ushort* wTl = wT + (full ? (size_t)l * LSTRIDE : 0);
    if (!full)
      k_prep<<<dim3(6912, 1), 256, 0, stream>>>(attn_w, proj_w, fc_w, fc2_w, wTl, l, 0);
    const ushort* qkvW = wTl;
    const ushort* projW = wTl + (size_t)3 * Csz * Csz;
    const ushort* fcW   = wTl + (size_t)4 * Csz * Csz;
    const ushort* fc2W  = wTl + (size_t)8 * Csz * Csz;

    // --- attention ---
    k_ln<<<Msz / 4, 256, 0, stream>>>(x, ln1_w + l * Csz, ln1_b + l * Csz, abuf);
    // qkv: 64x96 -> grid 768 = 3.0 CU-waves (no tail)
    k_gemm<64, 96, 2, 3, 64, 3, false, 0, true, 1><<<(Msz / 64) * (3 * Csz / 96), 256, 0, stream>>>(
        abuf, qkvW, attn_b + (size_t)l * 3 * Csz, nullptr, qkvbf, 3 * Csz, Csz, Msz / 64);
    k_attn<<<Bsz * Hsz * 16, 256, 0, stream>>>(qkvbf, abuf);
    // proj: 32x96 -> grid 512 = 2.0 waves, 2 blocks/CU (cross-block overlap)
    k_gemm<32, 96, 1, 3, 64, 0, false, 0, true, 1><<<(Msz / 32) * (Csz / 96), 256, 0, stream>>>(
        abuf, projW, proj_b + (size_t)l * Csz, x, x, Csz, Csz, Msz / 32);
    // --- mlp ---
    k_ln<<<Msz / 4, 256, 0, stream>>>(x, ln2_w + l * Csz, ln2_b + l * Csz, abuf);
    // fc: 64x128 -> grid 768 = 3.0 CU-waves (no tail)
    k_gemm<64, 128, 2, 4, 64, 2, false, 0, true, 1><<<(Msz / 64) * (4 * Csz / 128), 256, 0, stream>>>(
        abuf, fcW, fc_b + (size_t)l * 4 * Csz, nullptr, hbuf, 4 * Csz, Csz, Msz / 64);
    // fc2: 32x96 -> grid 512 = 2.0 waves, 2 blocks/CU (48 K-tiles no longer serial-exposed)
    k_gemm<32, 96, 1, 3, 64, 0, false, 0, true, 1><<<(Msz / 32) * (Csz / 96), 256, 0, stream>>>(
        hbuf, fc2W, fc2_b + (size_t)l * Csz, x, x, Csz, 4 * Csz, Msz / 32);
  }

  k_ln<<<Msz / 4, 256, 0, stream>>>(x, lnf_w, lnf_b, abuf);
  int ntm = Msz / 64;  // 32, m fastest
  // lm_head: R6-proven config — single-buffer, BK=64, 24.6 KB LDS, ~43-64% occ, ~2.4-2.55 TB/s
  k_gemm<64, 128, 2, 4, 64, 0, true, 0, false, 1><<<ntm * (VPAD / 128), 256, 0, stream>>>(
      abuf, lmw, nullptr, nullptr, out, Vsz, Csz, ntm);
}